// Round 12
// baseline (475.377 us; speedup 1.0000x reference)
//
#include <hip/hip_runtime.h>
#include <hip/hip_bf16.h>
#include <math.h>

#define NBP 64
#define NP  512
#define KK  20

using short8 = __attribute__((ext_vector_type(8))) short;
using f32x4  = __attribute__((ext_vector_type(4))) float;

// ---------------- workspace layout (bytes) — total 121,387,520 (== proven R2 footprint) ----
constexpr size_t O_X1   = 0;                      // float [64][64][512]                 8,388,608
constexpr size_t O_XCH  = 8388608;                // bf16  [64][512][320] hi            20,971,520
constexpr size_t O_XCL  = 29360128;               // bf16  [64][512][320] lo            20,971,520
constexpr size_t O_D    = 50331648;               // 67MB scratch (windows below)       67,108,864
constexpr size_t O_IDX  = 117440512;              // int  [64][512][20]                  2,621,440
constexpr size_t O_XX2  = 120061952;              // float[64][512]
constexpr size_t O_WC   = 120193024;              // float[64][512]  Wcat = [w2aT | wd2T]
constexpr size_t O_W3H  = 120324096;              // bf16 [512][320] hi
constexpr size_t O_W3L  = 120651776;              // bf16 [512][320] lo
constexpr size_t O_SC1  = 120979456;              // float[64][2]
constexpr size_t O_SC2  = 120979968;              // float[256][2]
constexpr size_t O_SC3  = 120982016;              // float[512][2]
constexpr size_t O_ST1  = 120986112;              // double[8][64][2]
constexpr size_t O_ST2  = 120994304;              // double[32][256][2]
constexpr size_t O_ST3  = 121125376;              // double[32][512][2] (ends 121,387,520)
constexpr size_t STATS_BYTES = 8192 + 131072 + 262144;

// async global->LDS, 16B per lane; LDS dest is wave-uniform base + lane*16
__device__ __forceinline__ void gload_lds16(const void* g, void* l) {
    __builtin_amdgcn_global_load_lds((const __attribute__((address_space(1))) unsigned int*)g,
                                     (__attribute__((address_space(3))) unsigned int*)l, 16, 0, 0);
}

// ---------------- prep: weight transposes + w3 bf16 split ----------------
__global__ __launch_bounds__(256) void prepw_kernel(const float* __restrict__ w2,
                                                    const float* __restrict__ w3,
                                                    float* __restrict__ Wcat,
                                                    __hip_bfloat16* __restrict__ w3h,
                                                    __hip_bfloat16* __restrict__ w3l) {
    int i = blockIdx.x * 256 + threadIdx.x;
    if (i < 32768) {                       // Wcat[c][q]: q<256 -> w2[q][c]; else wd2T
        int c = i >> 9, q = i & 511;
        Wcat[i] = (q < 256) ? w2[q * 128 + c]
                            : (w2[(q - 256) * 128 + 64 + c] - w2[(q - 256) * 128 + c]);
    } else if (i < 32768 + 163840) {       // w3 split, native [o][c] layout
        int j = i - 32768;
        float v = w3[j];
        __hip_bfloat16 h = __float2bfloat16(v);
        w3h[j] = h;
        w3l[j] = __float2bfloat16(v - __bfloat162float(h));
    }
}

// ---------------- wave top-20 SET selection (threshold method) ----------------
// v[8] per lane covers candidates m = lane + 64*q. Writes the top-20 index SET
// (value desc, ties -> lowest index — exactly jax.lax.top_k's selection) to
// outp[0..19] in arbitrary order. Downstream (max/min/sum over k) is
// order-invariant. Keys (value,index) are unique -> exact set semantics.
__device__ __forceinline__ void wave_top20_set(const float v[8], int lane, int* __restrict__ outp) {
    // monotone map f32 -> sortable u32
    unsigned u[8];
#pragma unroll
    for (int q = 0; q < 8; q++) {
        unsigned b = __float_as_uint(v[q]);
        u[q] = (b & 0x80000000u) ? ~b : (b | 0x80000000u);
    }
    // binary-search 20th-largest u, MSB-first bit build (wave-uniform, scalar pipe)
    unsigned T = 0u;
    for (int b = 31; b >= 0; b--) {
        unsigned cand = T | (1u << b);
        int cnt = 0;
#pragma unroll
        for (int q = 0; q < 8; q++)
            cnt += __popcll(__ballot(u[q] >= cand));
        if (cnt >= KK) T = cand;
    }
    unsigned long long lmask = (1ull << lane) - 1ull;
    // strict members: u > T
    int slotbase = 0;
#pragma unroll
    for (int q = 0; q < 8; q++) {
        unsigned long long bgt = __ballot(u[q] > T);
        if (u[q] > T) {
            int slot = slotbase + __popcll(bgt & lmask);
            outp[slot] = lane + (q << 6);
        }
        slotbase += __popcll(bgt);
    }
    // ties at T: fill remaining with smallest indices (q asc, lane asc == m asc)
    int need = KK - slotbase;
#pragma unroll
    for (int q = 0; q < 8; q++) {
        if (need > 0) {
            unsigned long long beq = __ballot(u[q] == T);
            int cq = __popcll(beq);
            int take = need < cq ? need : cq;
            if (u[q] == T) {
                int p = __popcll(beq & lmask);
                if (p < take) outp[slotbase + p] = lane + (q << 6);
            }
            slotbase += take;
            need -= take;
        }
    }
}

// ---------------- knn on raw 3-D points (wave per point) ----------------
__global__ __launch_bounds__(256) void knn1_kernel(const float* __restrict__ x, int* __restrict__ idx1) {
    __shared__ float px[NP * 3];
    __shared__ float sxx[NP];
    int bp = blockIdx.x >> 7;
    int pg = blockIdx.x & 127;
    int wid = threadIdx.x >> 6;
    int lane = threadIdx.x & 63;
    int n = pg * 4 + wid;
    const float* xb = x + (size_t)bp * NP * 3;
    for (int i = threadIdx.x; i < NP * 3; i += 256) px[i] = xb[i];
    __syncthreads();
    for (int i = threadIdx.x; i < NP; i += 256) {
        float a = px[i * 3], b = px[i * 3 + 1], c = px[i * 3 + 2];
        sxx[i] = a * a + b * b + c * c;
    }
    __syncthreads();
    float rn0 = px[n * 3], rn1 = px[n * 3 + 1], rn2 = px[n * 3 + 2];
    float xxn = sxx[n];
    float v[8];
#pragma unroll
    for (int q = 0; q < 8; q++) {
        int m = lane + (q << 6);
        float dot = rn0 * px[m * 3] + rn1 * px[m * 3 + 1] + rn2 * px[m * 3 + 2];
        v[q] = 2.0f * dot - xxn - sxx[m];
    }
    wave_top20_set(v, lane, idx1 + ((size_t)bp * NP + n) * KK);
}

// ---------------- conv1 (6->64) pre-BN, k-max/min + stats ----------------
__global__ __launch_bounds__(256) void conv1_kernel(const float* __restrict__ x, const float* __restrict__ w1,
                                                    const int* __restrict__ idx1,
                                                    float* __restrict__ h1max, float* __restrict__ h1min,
                                                    double* __restrict__ stats1) {
    __shared__ double red1[4][64][2];
    int bp = blockIdx.x >> 5;
    int nt = blockIdx.x & 31;
    int n0 = nt * 16;
    int o  = threadIdx.x & 63;
    int nq = threadIdx.x >> 6;
    const float* xb = x + (size_t)bp * NP * 3;
    float w[6];
#pragma unroll
    for (int c = 0; c < 6; c++) w[c] = w1[o * 6 + c];
    double s = 0.0, s2 = 0.0;
    float omx[4], omn[4];
#pragma unroll
    for (int nn = 0; nn < 4; nn++) {
        int n = n0 + nq * 4 + nn;
        float c0 = xb[n * 3], c1 = xb[n * 3 + 1], c2 = xb[n * 3 + 2];
        const int* ip = idx1 + ((size_t)bp * NP + n) * KK;
        float mx = -INFINITY, mn = INFINITY;
        for (int k = 0; k < KK; k++) {
            int j = ip[k];
            float e0 = xb[j * 3], e1 = xb[j * 3 + 1], e2 = xb[j * 3 + 2];
            float h = w[0] * (e0 - c0) + w[1] * (e1 - c1) + w[2] * (e2 - c2)
                    + w[3] * c0 + w[4] * c1 + w[5] * c2;
            mx = fmaxf(mx, h); mn = fminf(mn, h);
            s += (double)h; s2 += (double)h * (double)h;
        }
        omx[nn] = mx; omn[nn] = mn;
    }
    size_t base = ((size_t)bp * 64 + o) * NP + n0 + nq * 4;
    *(float4*)&h1max[base] = make_float4(omx[0], omx[1], omx[2], omx[3]);
    *(float4*)&h1min[base] = make_float4(omn[0], omn[1], omn[2], omn[3]);
    red1[nq][o][0] = s; red1[nq][o][1] = s2;
    __syncthreads();
    if (threadIdx.x < 64) {
        int oo = threadIdx.x;
        double S = 0, S2 = 0;
        for (int q = 0; q < 4; q++) { S += red1[q][oo][0]; S2 += red1[q][oo][1]; }
        int copy = blockIdx.x & 7;
        atomicAdd(&stats1[(copy * 64 + oo) * 2], S);
        atomicAdd(&stats1[(copy * 64 + oo) * 2 + 1], S2);
    }
}

// ---------------- generic BN finalize-prep ----------------
__global__ __launch_bounds__(256) void fprep_kernel(const double* __restrict__ stats, int ncopy, int nch,
                                                    double invN, const float* __restrict__ g,
                                                    const float* __restrict__ b, float* __restrict__ scsh) {
    int o = blockIdx.x * 256 + threadIdx.x;
    if (o >= nch) return;
    double S = 0, S2 = 0;
    for (int c = 0; c < ncopy; c++) {
        S  += stats[((size_t)c * nch + o) * 2];
        S2 += stats[((size_t)c * nch + o) * 2 + 1];
    }
    double m = S * invN;
    double v = S2 * invN - m * m;
    double sc = (double)g[o] / sqrt(v + 1e-5);
    scsh[o * 2]     = (float)sc;
    scsh[o * 2 + 1] = (float)((double)b[o] - sc * m);
}

// ---------------- finalize1: BN+lrelu, emit x1 (fp32) + XC[:, :64] (bf16 hi/lo) ------
__global__ __launch_bounds__(256) void fin1_kernel(const float* __restrict__ h1max, const float* __restrict__ h1min,
                                                   const float* __restrict__ scsh,
                                                   float* __restrict__ x1,
                                                   __hip_bfloat16* __restrict__ XCh,
                                                   __hip_bfloat16* __restrict__ XCl) {
    __shared__ float tile[64][33];
    int bp = blockIdx.x >> 4, nt = blockIdx.x & 15, n0 = nt * 32;
    for (int i = threadIdx.x; i < 64 * 32; i += 256) {
        int o = i >> 5, nl = i & 31;
        float sc = scsh[o * 2], sh = scsh[o * 2 + 1];
        size_t gi = ((size_t)bp * 64 + o) * NP + n0 + nl;
        float v = (sc >= 0.0f) ? h1max[gi] : h1min[gi];
        float y = sc * v + sh;
        y = (y >= 0.0f) ? y : 0.2f * y;
        x1[gi] = y;
        tile[o][nl] = y;
    }
    __syncthreads();
    for (int i = threadIdx.x; i < 64 * 32; i += 256) {
        int nl = i >> 6, o = i & 63;
        float y = tile[o][nl];
        __hip_bfloat16 h = __float2bfloat16(y);
        size_t base = ((size_t)bp * NP + n0 + nl) * 320 + o;
        XCh[base] = h;
        XCl[base] = __float2bfloat16(y - __bfloat162float(h));
    }
}

// ---------------- xx for knn2 (reads x1 column-coalesced; same fmac chain as gram) ----
__global__ __launch_bounds__(256) void xx2_kernel(const float* __restrict__ x1, float* __restrict__ xx2v) {
    int i = blockIdx.x * 256 + threadIdx.x;
    int bp = i >> 9, n = i & 511;
    const float* xb = x1 + (size_t)bp * 64 * NP + n;
    float acc = 0.0f;
    for (int c = 0; c < 64; c++) { float v = xb[c * NP]; acc += v * v; }
    xx2v[i] = acc;
}

// ---------------- gram: neg_dist[bp][n][m] (stays fp32 — feeds top-k selection) ------
__global__ __launch_bounds__(256) void gram_kernel(const float* __restrict__ x1, const float* __restrict__ xx2v,
                                                   float* __restrict__ Dm) {
    __shared__ float An[64 * 128];
    __shared__ float Bm[64 * 128];
    int bp = blockIdx.x >> 4;
    int ntb = (blockIdx.x >> 2) & 3, mtb = blockIdx.x & 3;
    int n0 = ntb * 128, m0 = mtb * 128;
    const float* xb = x1 + (size_t)bp * 64 * NP;
    for (int i = threadIdx.x; i < 64 * 128; i += 256) {
        int c = i >> 7, r = i & 127;
        An[i] = xb[c * NP + n0 + r];
        Bm[i] = xb[c * NP + m0 + r];
    }
    __syncthreads();
    int ng = threadIdx.x & 15, mg = threadIdx.x >> 4;
    float acc[8][8];
#pragma unroll
    for (int r = 0; r < 8; r++)
#pragma unroll
        for (int j = 0; j < 8; j++) acc[r][j] = 0.0f;
    const float* ap = An + ng * 8;
    const float* bq = Bm + mg * 8;
#pragma unroll 2
    for (int c = 0; c < 64; c++) {
        float4 a0 = *(const float4*)(ap + c * 128);
        float4 a1 = *(const float4*)(ap + c * 128 + 4);
        float4 b0 = *(const float4*)(bq + c * 128);
        float4 b1 = *(const float4*)(bq + c * 128 + 4);
        float av[8] = {a0.x, a0.y, a0.z, a0.w, a1.x, a1.y, a1.z, a1.w};
        float bv[8] = {b0.x, b0.y, b0.z, b0.w, b1.x, b1.y, b1.z, b1.w};
#pragma unroll
        for (int r = 0; r < 8; r++)
#pragma unroll
            for (int j = 0; j < 8; j++) acc[r][j] += av[r] * bv[j];
    }
    float xm[8];
#pragma unroll
    for (int j = 0; j < 8; j++) xm[j] = xx2v[bp * NP + m0 + mg * 8 + j];
#pragma unroll
    for (int r = 0; r < 8; r++) {
        float xxn = xx2v[bp * NP + n0 + ng * 8 + r];
        float out[8];
#pragma unroll
        for (int j = 0; j < 8; j++) out[j] = 2.0f * acc[r][j] - xxn - xm[j];
        size_t base = ((size_t)bp * NP + n0 + ng * 8 + r) * NP + m0 + mg * 8;
        *(float4*)&Dm[base]     = make_float4(out[0], out[1], out[2], out[3]);
        *(float4*)&Dm[base + 4] = make_float4(out[4], out[5], out[6], out[7]);
    }
}

// ---------------- top-20 per row of neg_dist (wave per row) ----------------
__global__ __launch_bounds__(256) void topk2_kernel(const float* __restrict__ Dm, int* __restrict__ idx2) {
    int wid = threadIdx.x >> 6;
    int lane = threadIdx.x & 63;
    int row = blockIdx.x * 4 + wid;
    const float* dr = Dm + (size_t)row * NP;
    float v[8];
#pragma unroll
    for (int q = 0; q < 8; q++) v[q] = dr[lane + (q << 6)];
    wave_top20_set(v, lane, idx2 + (size_t)row * KK);
}

// ---------------- conv2a: A[j][o]=w2a·x1[j], Dt[n][o]=wd2·x1[n] (one GEMM) ----------
__global__ __launch_bounds__(256) void conv2a_kernel(const float* __restrict__ x1, const float* __restrict__ Wcat,
                                                     float* __restrict__ Aout, float* __restrict__ Dtout) {
    __shared__ float An[64 * 128];
    __shared__ float Bm[64 * 128];
    int bp = blockIdx.x >> 4;
    int ntb = (blockIdx.x >> 2) & 3, qtb = blockIdx.x & 3;
    int n0 = ntb * 128, q0 = qtb * 128;
    const float* xb = x1 + (size_t)bp * 64 * NP;
    for (int i = threadIdx.x; i < 64 * 128; i += 256) {
        int c = i >> 7, r = i & 127;
        An[i] = xb[c * NP + n0 + r];
        Bm[i] = Wcat[c * 512 + q0 + r];
    }
    __syncthreads();
    int ng = threadIdx.x & 15, mg = threadIdx.x >> 4;
    float acc[8][8];
#pragma unroll
    for (int r = 0; r < 8; r++)
#pragma unroll
        for (int j = 0; j < 8; j++) acc[r][j] = 0.0f;
    const float* ap = An + ng * 8;
    const float* bq = Bm + mg * 8;
#pragma unroll 2
    for (int c = 0; c < 64; c++) {
        float4 a0 = *(const float4*)(ap + c * 128);
        float4 a1 = *(const float4*)(ap + c * 128 + 4);
        float4 b0 = *(const float4*)(bq + c * 128);
        float4 b1 = *(const float4*)(bq + c * 128 + 4);
        float av[8] = {a0.x, a0.y, a0.z, a0.w, a1.x, a1.y, a1.z, a1.w};
        float bv[8] = {b0.x, b0.y, b0.z, b0.w, b1.x, b1.y, b1.z, b1.w};
#pragma unroll
        for (int r = 0; r < 8; r++)
#pragma unroll
            for (int j = 0; j < 8; j++) acc[r][j] += av[r] * bv[j];
    }
    float* ob = (q0 < 256) ? Aout : Dtout;
    int qoff = (q0 & 255) + mg * 8;
#pragma unroll
    for (int r = 0; r < 8; r++) {
        size_t base = ((size_t)bp * NP + n0 + ng * 8 + r) * 256 + qoff;
        *(float4*)&ob[base]     = make_float4(acc[r][0], acc[r][1], acc[r][2], acc[r][3]);
        *(float4*)&ob[base + 4] = make_float4(acc[r][4], acc[r][5], acc[r][6], acc[r][7]);
    }
}

// ---------------- conv2b: stats only (gather over k) ----------------
__global__ __launch_bounds__(256) void conv2b_kernel(const float* __restrict__ A, const float* __restrict__ Dt,
                                                     const int* __restrict__ idx2,
                                                     double* __restrict__ stats2) {
    __shared__ float Al[512 * 16];
    __shared__ double red[16][16][2];
    int bid = blockIdx.x;
    int bp = bid >> 5;
    int ot = (bid >> 1) & 15, nh = bid & 1;
    int o0 = ot * 16, n0 = nh * 256;
    int tid = threadIdx.x;
    for (int i = tid; i < 2048; i += 256) {
        int j = i >> 2, p = i & 3;
        *(float4*)&Al[j * 16 + p * 4] = *(const float4*)&A[((size_t)bp * NP + j) * 256 + o0 + p * 4];
    }
    __syncthreads();
    int o = tid & 15, np = tid >> 4;
    double sh = 0.0, sh2 = 0.0;
    for (int nn = 0; nn < 16; nn++) {
        int n = n0 + np * 16 + nn;
        const int* ip = idx2 + ((size_t)bp * NP + n) * KK;
        int4 ia = *(const int4*)ip, ib = *(const int4*)(ip + 4), ic = *(const int4*)(ip + 8);
        int4 id4 = *(const int4*)(ip + 12), ie = *(const int4*)(ip + 16);
        int js[20] = {ia.x, ia.y, ia.z, ia.w, ib.x, ib.y, ib.z, ib.w, ic.x, ic.y, ic.z, ic.w,
                      id4.x, id4.y, id4.z, id4.w, ie.x, ie.y, ie.z, ie.w};
        float dv = Dt[((size_t)bp * NP + n) * 256 + o0 + o];
        float s1 = 0.0f, s2 = 0.0f;
#pragma unroll
        for (int k = 0; k < KK; k++) {
            float a = Al[js[k] * 16 + o];
            s1 += a; s2 += a * a;
        }
        sh  += (double)s1 + 20.0 * (double)dv;
        sh2 += (double)s2 + 2.0 * (double)dv * (double)s1 + 20.0 * (double)dv * (double)dv;
    }
    red[np][o][0] = sh; red[np][o][1] = sh2;
    __syncthreads();
    if (tid < 16) {
        double S = 0, S2 = 0;
        for (int q = 0; q < 16; q++) { S += red[q][tid][0]; S2 += red[q][tid][1]; }
        int copy = bid & 31;
        atomicAdd(&stats2[(copy * 256 + o0 + tid) * 2], S);
        atomicAdd(&stats2[(copy * 256 + o0 + tid) * 2 + 1], S2);
    }
}

// ---------------- fin2g: re-gather, BN+lrelu, emit XC[:, 64:320] (bf16 hi/lo) --------
__global__ __launch_bounds__(256) void fin2g_kernel(const float* __restrict__ A, const float* __restrict__ Dt,
                                                    const int* __restrict__ idx2,
                                                    const float* __restrict__ scsh,
                                                    __hip_bfloat16* __restrict__ XCh,
                                                    __hip_bfloat16* __restrict__ XCl) {
    __shared__ float Al[512 * 16];
    int bid = blockIdx.x;
    int bp = bid >> 5;
    int ot = (bid >> 1) & 15, nh = bid & 1;
    int o0 = ot * 16, n0 = nh * 256;
    int tid = threadIdx.x;
    for (int i = tid; i < 2048; i += 256) {
        int j = i >> 2, p = i & 3;
        *(float4*)&Al[j * 16 + p * 4] = *(const float4*)&A[((size_t)bp * NP + j) * 256 + o0 + p * 4];
    }
    __syncthreads();
    int o = tid & 15, np = tid >> 4;
    float sc = scsh[(o0 + o) * 2], shift = scsh[(o0 + o) * 2 + 1];
    for (int nn = 0; nn < 16; nn++) {
        int n = n0 + np * 16 + nn;
        const int* ip = idx2 + ((size_t)bp * NP + n) * KK;
        int4 ia = *(const int4*)ip, ib = *(const int4*)(ip + 4), ic = *(const int4*)(ip + 8);
        int4 id4 = *(const int4*)(ip + 12), ie = *(const int4*)(ip + 16);
        int js[20] = {ia.x, ia.y, ia.z, ia.w, ib.x, ib.y, ib.z, ib.w, ic.x, ic.y, ic.z, ic.w,
                      id4.x, id4.y, id4.z, id4.w, ie.x, ie.y, ie.z, ie.w};
        float dv = Dt[((size_t)bp * NP + n) * 256 + o0 + o];
        float mx = -INFINITY, mn = INFINITY;
#pragma unroll
        for (int k = 0; k < KK; k++) {
            float a = Al[js[k] * 16 + o];
            mx = fmaxf(mx, a); mn = fminf(mn, a);
        }
        float v = ((sc >= 0.0f) ? mx : mn) + dv;
        float y = sc * v + shift;
        y = (y >= 0.0f) ? y : 0.2f * y;
        __hip_bfloat16 h = __float2bfloat16(y);
        size_t base = ((size_t)bp * NP + n) * 320 + 64 + o0 + o;
        XCh[base] = h;
        XCl[base] = __float2bfloat16(y - __bfloat162float(h));
    }
}

// ---------------- conv3m: split-bf16 MFMA GEMM (320->512), 128x128 tile, K=64 -------
// Staging via global_load_lds (linear LDS dest, XOR-swizzled SOURCE chunk —
// same final LDS placement as before -> bitwise-identical h3). 64 KB LDS.
__global__ __launch_bounds__(256) void conv3m_kernel(const __hip_bfloat16* __restrict__ XCh,
                                                     const __hip_bfloat16* __restrict__ XCl,
                                                     const __hip_bfloat16* __restrict__ w3h,
                                                     const __hip_bfloat16* __restrict__ w3l,
                                                     float* __restrict__ h3,
                                                     double* __restrict__ stats3) {
    // rows: Wh[0:128) Wl[128:256) Xh[256:384) Xl[384:512) — 512 rows × 128B = 64 KB
    __shared__ __align__(16) __hip_bfloat16 smem3[512 * 64];
    int bid = blockIdx.x;
    int bp = bid >> 4, ot = (bid >> 2) & 3, nt = bid & 3;
    int o0 = ot * 128, n0 = nt * 128;
    int tid = threadIdx.x, l = tid & 63, w = tid >> 6;
    int wo = (w >> 1) * 64, wn = (w & 1) * 64;
    int lrow = l & 15, lj = l >> 4;
    f32x4 z4 = {0.f, 0.f, 0.f, 0.f};
    f32x4 acc[4][4];
#pragma unroll
    for (int mt = 0; mt < 4; mt++)
#pragma unroll
        for (int nl = 0; nl < 4; nl++) acc[mt][nl] = z4;
    for (int ct = 0; ct < 5; ct++) {
        int c0 = ct * 64;
        __syncthreads();
#pragma unroll
        for (int g = 0; g < 16; g++) {
            int grp = w * 16 + g;              // 8-row group; regions at multiples of 8
            int row = grp * 8 + (l >> 3);
            int ch  = l & 7;
            const __hip_bfloat16* srcrow;
            if (row < 128)      srcrow = w3h + (size_t)(o0 + row) * 320;
            else if (row < 256) srcrow = w3l + (size_t)(o0 + row - 128) * 320;
            else if (row < 384) srcrow = XCh + ((size_t)bp * NP + n0 + row - 256) * 320;
            else                srcrow = XCl + ((size_t)bp * NP + n0 + row - 384) * 320;
            gload_lds16(srcrow + c0 + ((ch ^ (row & 7)) * 8), smem3 + grp * 512);
        }
        __syncthreads();
#pragma unroll
        for (int ks = 0; ks < 2; ks++) {
            short8 ah[4], alo[4], bh[4], blo[4];
#pragma unroll
            for (int t = 0; t < 4; t++) {
                int r = wo + t * 16 + lrow;
                int c = (lj + 4 * ks) ^ (r & 7);
                ah[t]  = *(const short8*)(smem3 + r * 64 + c * 8);
                alo[t] = *(const short8*)(smem3 + (128 + r) * 64 + c * 8);
                int r2 = wn + t * 16 + lrow;
                int c2 = (lj + 4 * ks) ^ (r2 & 7);
                bh[t]  = *(const short8*)(smem3 + (256 + r2) * 64 + c2 * 8);
                blo[t] = *(const short8*)(smem3 + (384 + r2) * 64 + c2 * 8);
            }
#pragma unroll
            for (int mt = 0; mt < 4; mt++)
#pragma unroll
                for (int nl = 0; nl < 4; nl++) {
                    acc[mt][nl] = __builtin_amdgcn_mfma_f32_16x16x32_bf16(alo[mt], bh[nl], acc[mt][nl], 0, 0, 0);
                    acc[mt][nl] = __builtin_amdgcn_mfma_f32_16x16x32_bf16(ah[mt], blo[nl], acc[mt][nl], 0, 0, 0);
                    acc[mt][nl] = __builtin_amdgcn_mfma_f32_16x16x32_bf16(ah[mt], bh[nl], acc[mt][nl], 0, 0, 0);
                }
        }
    }
    __syncthreads();                    // all LDS reads done; reuse smem for reduction
    double* redD = (double*)smem3;      // [2 n-half][128 o_local][2]
    size_t hb = (size_t)bp * 512;
#pragma unroll
    for (int mt = 0; mt < 4; mt++) {
#pragma unroll
        for (int rg = 0; rg < 4; rg++) {
            int ol = wo + mt * 16 + lj * 4 + rg;
            double s = 0.0, s2 = 0.0;
#pragma unroll
            for (int nl = 0; nl < 4; nl++) {
                float h = acc[mt][nl][rg];
                int ng = n0 + wn + nl * 16 + lrow;
                h3[(hb + o0 + ol) * 512 + ng] = h;
                s += (double)h; s2 += (double)h * (double)h;
            }
#pragma unroll
            for (int off = 1; off < 16; off <<= 1) {
                s  += __shfl_xor(s, off);
                s2 += __shfl_xor(s2, off);
            }
            if (lrow == 0) {
                redD[((w & 1) * 128 + ol) * 2]     = s;
                redD[((w & 1) * 128 + ol) * 2 + 1] = s2;
            }
        }
    }
    __syncthreads();
    if (tid < 128) {
        double S  = redD[tid * 2]     + redD[(128 + tid) * 2];
        double S2 = redD[tid * 2 + 1] + redD[(128 + tid) * 2 + 1];
        int copy = bid & 31;
        atomicAdd(&stats3[(copy * 512 + o0 + tid) * 2], S);
        atomicAdd(&stats3[(copy * 512 + o0 + tid) * 2 + 1], S2);
    }
}

// ---------------- pool: BN+lrelu then max & mean over n ----------------
__global__ __launch_bounds__(256) void pool_kernel(const float* __restrict__ h3, const float* __restrict__ scsh3,
                                                   float* __restrict__ out) {
    int row = blockIdx.x * 4 + (threadIdx.x >> 6);
    int lane = threadIdx.x & 63;
    int bp = row >> 9, o = row & 511;
    float sc = scsh3[o * 2], sh = scsh3[o * 2 + 1];
    const float* hr = h3 + (size_t)row * NP;
    float4 v0 = *(const float4*)&hr[lane * 4];
    float4 v1 = *(const float4*)&hr[256 + lane * 4];
    float vs[8] = {v0.x, v0.y, v0.z, v0.w, v1.x, v1.y, v1.z, v1.w};
    float mx = -INFINITY, sm = 0.0f;
#pragma unroll
    for (int q = 0; q < 8; q++) {
        float y = sc * vs[q] + sh;
        y = (y >= 0.0f) ? y : 0.2f * y;
        mx = fmaxf(mx, y); sm += y;
    }
    for (int off = 32; off >= 1; off >>= 1) {
        mx = fmaxf(mx, __shfl_xor(mx, off));
        sm += __shfl_xor(sm, off);
    }
    if (lane == 0) {
        out[(size_t)bp * 1024 + o]       = mx;
        out[(size_t)bp * 1024 + 512 + o] = sm * (1.0f / 512.0f);
    }
}

extern "C" void kernel_launch(void* const* d_in, const int* in_sizes, int n_in,
                              void* d_out, int out_size, void* d_ws, size_t ws_size,
                              hipStream_t stream) {
    const float* x  = (const float*)d_in[0];
    const float* w1 = (const float*)d_in[1];
    const float* g1 = (const float*)d_in[2];
    const float* b1 = (const float*)d_in[3];
    const float* w2 = (const float*)d_in[4];
    const float* g2 = (const float*)d_in[5];
    const float* b2 = (const float*)d_in[6];
    const float* w3 = (const float*)d_in[7];
    const float* g3 = (const float*)d_in[8];
    const float* b3 = (const float*)d_in[9];
    float* out = (float*)d_out;
    char* ws = (char*)d_ws;

    float*          x1    = (float*)(ws + O_X1);
    __hip_bfloat16* XCh   = (__hip_bfloat16*)(ws + O_XCH);
    __hip_bfloat16* XCl   = (__hip_bfloat16*)(ws + O_XCL);
    float*          Dbuf  = (float*)(ws + O_D);
    int*            idx   = (int*)(ws + O_IDX);
    float*          xx2v  = (float*)(ws + O_XX2);
    float*          Wcat  = (float*)(ws + O_WC);
    __hip_bfloat16* w3h   = (__hip_bfloat16*)(ws + O_W3H);
    __hip_bfloat16* w3l   = (__hip_bfloat16*)(ws + O_W3L);
    float*          scsh1 = (float*)(ws + O_SC1);
    float*          scsh2 = (float*)(ws + O_SC2);
    float*          scsh3 = (float*)(ws + O_SC3);
    double*         st1   = (double*)(ws + O_ST1);
    double*         st2   = (double*)(ws + O_ST2);
    double*         st3   = (double*)(ws + O_ST3);

    // D-region windows (sequential lifetimes)
    float* h1max = Dbuf;
    float* h1min = Dbuf + 2097152;
    float* Abuf  = Dbuf;                  // [64][512][256]
    float* Dt    = Dbuf + 8388608;        // [64][512][256] (floats; +33,554,432 B)
    float* h3    = Dbuf;                  // [64][512][512]

    hipMemsetAsync(ws + O_ST1, 0, STATS_BYTES, stream);
    prepw_kernel<<<768, 256, 0, stream>>>(w2, w3, Wcat, w3h, w3l);
    knn1_kernel<<<8192, 256, 0, stream>>>(x, idx);
    conv1_kernel<<<2048, 256, 0, stream>>>(x, w1, idx, h1max, h1min, st1);
    fprep_kernel<<<1, 256, 0, stream>>>(st1, 8, 64, 1.0 / 655360.0, g1, b1, scsh1);
    fin1_kernel<<<1024, 256, 0, stream>>>(h1max, h1min, scsh1, x1, XCh, XCl);
    xx2_kernel<<<128, 256, 0, stream>>>(x1, xx2v);
    gram_kernel<<<1024, 256, 0, stream>>>(x1, xx2v, Dbuf);
    topk2_kernel<<<8192, 256, 0, stream>>>(Dbuf, idx);
    conv2a_kernel<<<1024, 256, 0, stream>>>(x1, Wcat, Abuf, Dt);
    conv2b_kernel<<<2048, 256, 0, stream>>>(Abuf, Dt, idx, st2);
    fprep_kernel<<<1, 256, 0, stream>>>(st2, 32, 256, 1.0 / 655360.0, g2, b2, scsh2);
    fin2g_kernel<<<2048, 256, 0, stream>>>(Abuf, Dt, idx, scsh2, XCh, XCl);
    conv3m_kernel<<<1024, 256, 0, stream>>>(XCh, XCl, w3h, w3l, h3, st3);
    fprep_kernel<<<2, 256, 0, stream>>>(st3, 32, 512, 1.0 / 32768.0, g3, b3, scsh3);
    pool_kernel<<<8192, 256, 0, stream>>>(h3, scsh3, out);
}

// Round 13
// 448.527 us; speedup vs baseline: 1.0599x; 1.0599x over previous
//
#include <hip/hip_runtime.h>
#include <hip/hip_bf16.h>
#include <math.h>

#define NBP 64
#define NP  512
#define KK  20

using short8 = __attribute__((ext_vector_type(8))) short;
using f32x4  = __attribute__((ext_vector_type(4))) float;

// ---------------- workspace layout (bytes) — total 121,387,520 (== proven R2 footprint) ----
constexpr size_t O_X1   = 0;                      // float [64][64][512]                 8,388,608
constexpr size_t O_XCH  = 8388608;                // bf16  [64][512][320] hi            20,971,520
constexpr size_t O_XCL  = 29360128;               // bf16  [64][512][320] lo            20,971,520
constexpr size_t O_D    = 50331648;               // 67MB scratch (windows below)       67,108,864
constexpr size_t O_IDX  = 117440512;              // int  [64][512][20]                  2,621,440
constexpr size_t O_XX2  = 120061952;              // float[64][512]
constexpr size_t O_WC   = 120193024;              // float[64][512]  Wcat = [w2aT | wd2T]
constexpr size_t O_W3H  = 120324096;              // bf16 [512][320] hi
constexpr size_t O_W3L  = 120651776;              // bf16 [512][320] lo
constexpr size_t O_SC1  = 120979456;              // float[64][2]
constexpr size_t O_SC2  = 120979968;              // float[256][2]
constexpr size_t O_SC3  = 120982016;              // float[512][2]
constexpr size_t O_ST1  = 120986112;              // double[8][64][2]
constexpr size_t O_ST2  = 120994304;              // double[32][256][2]
constexpr size_t O_ST3  = 121125376;              // double[32][512][2] (ends 121,387,520)
constexpr size_t STATS_BYTES = 8192 + 131072 + 262144;

// ---------------- prep: weight transposes + w3 bf16 split ----------------
__global__ __launch_bounds__(256) void prepw_kernel(const float* __restrict__ w2,
                                                    const float* __restrict__ w3,
                                                    float* __restrict__ Wcat,
                                                    __hip_bfloat16* __restrict__ w3h,
                                                    __hip_bfloat16* __restrict__ w3l) {
    int i = blockIdx.x * 256 + threadIdx.x;
    if (i < 32768) {                       // Wcat[c][q]: q<256 -> w2[q][c]; else wd2T
        int c = i >> 9, q = i & 511;
        Wcat[i] = (q < 256) ? w2[q * 128 + c]
                            : (w2[(q - 256) * 128 + 64 + c] - w2[(q - 256) * 128 + c]);
    } else if (i < 32768 + 163840) {       // w3 split, native [o][c] layout
        int j = i - 32768;
        float v = w3[j];
        __hip_bfloat16 h = __float2bfloat16(v);
        w3h[j] = h;
        w3l[j] = __float2bfloat16(v - __bfloat162float(h));
    }
}

// ---------------- wave top-20 SET selection (threshold method) ----------------
// v[8] per lane covers candidates m = lane + 64*q. Writes the top-20 index SET
// (value desc, ties -> lowest index — exactly jax.lax.top_k's selection) to
// outp[0..19] in arbitrary order. Downstream (max/min/sum over k) is
// order-invariant. Keys (value,index) are unique -> exact set semantics.
__device__ __forceinline__ void wave_top20_set(const float v[8], int lane, int* __restrict__ outp) {
    // monotone map f32 -> sortable u32
    unsigned u[8];
#pragma unroll
    for (int q = 0; q < 8; q++) {
        unsigned b = __float_as_uint(v[q]);
        u[q] = (b & 0x80000000u) ? ~b : (b | 0x80000000u);
    }
    // binary-search 20th-largest u, MSB-first bit build (wave-uniform, scalar pipe)
    unsigned T = 0u;
    for (int b = 31; b >= 0; b--) {
        unsigned cand = T | (1u << b);
        int cnt = 0;
#pragma unroll
        for (int q = 0; q < 8; q++)
            cnt += __popcll(__ballot(u[q] >= cand));
        if (cnt >= KK) T = cand;
    }
    unsigned long long lmask = (1ull << lane) - 1ull;
    // strict members: u > T
    int slotbase = 0;
#pragma unroll
    for (int q = 0; q < 8; q++) {
        unsigned long long bgt = __ballot(u[q] > T);
        if (u[q] > T) {
            int slot = slotbase + __popcll(bgt & lmask);
            outp[slot] = lane + (q << 6);
        }
        slotbase += __popcll(bgt);
    }
    // ties at T: fill remaining with smallest indices (q asc, lane asc == m asc)
    int need = KK - slotbase;
#pragma unroll
    for (int q = 0; q < 8; q++) {
        if (need > 0) {
            unsigned long long beq = __ballot(u[q] == T);
            int cq = __popcll(beq);
            int take = need < cq ? need : cq;
            if (u[q] == T) {
                int p = __popcll(beq & lmask);
                if (p < take) outp[slotbase + p] = lane + (q << 6);
            }
            slotbase += take;
            need -= take;
        }
    }
}

// ---------------- knn on raw 3-D points (wave per point) ----------------
__global__ __launch_bounds__(256) void knn1_kernel(const float* __restrict__ x, int* __restrict__ idx1) {
    __shared__ float px[NP * 3];
    __shared__ float sxx[NP];
    int bp = blockIdx.x >> 7;
    int pg = blockIdx.x & 127;
    int wid = threadIdx.x >> 6;
    int lane = threadIdx.x & 63;
    int n = pg * 4 + wid;
    const float* xb = x + (size_t)bp * NP * 3;
    for (int i = threadIdx.x; i < NP * 3; i += 256) px[i] = xb[i];
    __syncthreads();
    for (int i = threadIdx.x; i < NP; i += 256) {
        float a = px[i * 3], b = px[i * 3 + 1], c = px[i * 3 + 2];
        sxx[i] = a * a + b * b + c * c;
    }
    __syncthreads();
    float rn0 = px[n * 3], rn1 = px[n * 3 + 1], rn2 = px[n * 3 + 2];
    float xxn = sxx[n];
    float v[8];
#pragma unroll
    for (int q = 0; q < 8; q++) {
        int m = lane + (q << 6);
        float dot = rn0 * px[m * 3] + rn1 * px[m * 3 + 1] + rn2 * px[m * 3 + 2];
        v[q] = 2.0f * dot - xxn - sxx[m];
    }
    wave_top20_set(v, lane, idx1 + ((size_t)bp * NP + n) * KK);
}

// ---------------- conv1 (6->64) pre-BN, k-max/min + stats (LDS point cache) ---------
__global__ __launch_bounds__(256) void conv1_kernel(const float* __restrict__ x, const float* __restrict__ w1,
                                                    const int* __restrict__ idx1,
                                                    float* __restrict__ h1max, float* __restrict__ h1min,
                                                    double* __restrict__ stats1) {
    __shared__ float px[NP * 3];
    __shared__ double red1[4][64][2];
    int bp = blockIdx.x >> 5;
    int nt = blockIdx.x & 31;
    int n0 = nt * 16;
    int o  = threadIdx.x & 63;
    int nq = threadIdx.x >> 6;
    const float* xb = x + (size_t)bp * NP * 3;
    for (int i = threadIdx.x; i < NP * 3; i += 256) px[i] = xb[i];
    float w[6];
#pragma unroll
    for (int c = 0; c < 6; c++) w[c] = w1[o * 6 + c];
    __syncthreads();
    double s = 0.0, s2 = 0.0;
    float omx[4], omn[4];
#pragma unroll
    for (int nn = 0; nn < 4; nn++) {
        int n = n0 + nq * 4 + nn;
        float c0 = px[n * 3], c1 = px[n * 3 + 1], c2 = px[n * 3 + 2];
        const int* ip = idx1 + ((size_t)bp * NP + n) * KK;
        float mx = -INFINITY, mn = INFINITY;
        for (int k = 0; k < KK; k++) {
            int j = ip[k];
            float e0 = px[j * 3], e1 = px[j * 3 + 1], e2 = px[j * 3 + 2];
            float h = w[0] * (e0 - c0) + w[1] * (e1 - c1) + w[2] * (e2 - c2)
                    + w[3] * c0 + w[4] * c1 + w[5] * c2;
            mx = fmaxf(mx, h); mn = fminf(mn, h);
            s += (double)h; s2 += (double)h * (double)h;
        }
        omx[nn] = mx; omn[nn] = mn;
    }
    size_t base = ((size_t)bp * 64 + o) * NP + n0 + nq * 4;
    *(float4*)&h1max[base] = make_float4(omx[0], omx[1], omx[2], omx[3]);
    *(float4*)&h1min[base] = make_float4(omn[0], omn[1], omn[2], omn[3]);
    red1[nq][o][0] = s; red1[nq][o][1] = s2;
    __syncthreads();
    if (threadIdx.x < 64) {
        int oo = threadIdx.x;
        double S = 0, S2 = 0;
        for (int q = 0; q < 4; q++) { S += red1[q][oo][0]; S2 += red1[q][oo][1]; }
        int copy = blockIdx.x & 7;
        atomicAdd(&stats1[(copy * 64 + oo) * 2], S);
        atomicAdd(&stats1[(copy * 64 + oo) * 2 + 1], S2);
    }
}

// ---------------- generic BN finalize-prep ----------------
__global__ __launch_bounds__(256) void fprep_kernel(const double* __restrict__ stats, int ncopy, int nch,
                                                    double invN, const float* __restrict__ g,
                                                    const float* __restrict__ b, float* __restrict__ scsh) {
    int o = blockIdx.x * 256 + threadIdx.x;
    if (o >= nch) return;
    double S = 0, S2 = 0;
    for (int c = 0; c < ncopy; c++) {
        S  += stats[((size_t)c * nch + o) * 2];
        S2 += stats[((size_t)c * nch + o) * 2 + 1];
    }
    double m = S * invN;
    double v = S2 * invN - m * m;
    double sc = (double)g[o] / sqrt(v + 1e-5);
    scsh[o * 2]     = (float)sc;
    scsh[o * 2 + 1] = (float)((double)b[o] - sc * m);
}

// ---------------- finalize1: BN+lrelu, emit x1 (fp32) + XC[:, :64] (bf16 hi/lo) ------
__global__ __launch_bounds__(256) void fin1_kernel(const float* __restrict__ h1max, const float* __restrict__ h1min,
                                                   const float* __restrict__ scsh,
                                                   float* __restrict__ x1,
                                                   __hip_bfloat16* __restrict__ XCh,
                                                   __hip_bfloat16* __restrict__ XCl) {
    __shared__ float tile[64][33];
    int bp = blockIdx.x >> 4, nt = blockIdx.x & 15, n0 = nt * 32;
    for (int i = threadIdx.x; i < 64 * 32; i += 256) {
        int o = i >> 5, nl = i & 31;
        float sc = scsh[o * 2], sh = scsh[o * 2 + 1];
        size_t gi = ((size_t)bp * 64 + o) * NP + n0 + nl;
        float v = (sc >= 0.0f) ? h1max[gi] : h1min[gi];
        float y = sc * v + sh;
        y = (y >= 0.0f) ? y : 0.2f * y;
        x1[gi] = y;
        tile[o][nl] = y;
    }
    __syncthreads();
    for (int i = threadIdx.x; i < 64 * 32; i += 256) {
        int nl = i >> 6, o = i & 63;
        float y = tile[o][nl];
        __hip_bfloat16 h = __float2bfloat16(y);
        size_t base = ((size_t)bp * NP + n0 + nl) * 320 + o;
        XCh[base] = h;
        XCl[base] = __float2bfloat16(y - __bfloat162float(h));
    }
}

// ---------------- xx for knn2 (reads x1 column-coalesced; same fmac chain as gram) ----
__global__ __launch_bounds__(256) void xx2_kernel(const float* __restrict__ x1, float* __restrict__ xx2v) {
    int i = blockIdx.x * 256 + threadIdx.x;
    int bp = i >> 9, n = i & 511;
    const float* xb = x1 + (size_t)bp * 64 * NP + n;
    float acc = 0.0f;
    for (int c = 0; c < 64; c++) { float v = xb[c * NP]; acc += v * v; }
    xx2v[i] = acc;
}

// ---------------- gram: neg_dist[bp][n][m] (stays fp32 — feeds top-k selection) ------
__global__ __launch_bounds__(256) void gram_kernel(const float* __restrict__ x1, const float* __restrict__ xx2v,
                                                   float* __restrict__ Dm) {
    __shared__ float An[64 * 128];
    __shared__ float Bm[64 * 128];
    int bp = blockIdx.x >> 4;
    int ntb = (blockIdx.x >> 2) & 3, mtb = blockIdx.x & 3;
    int n0 = ntb * 128, m0 = mtb * 128;
    const float* xb = x1 + (size_t)bp * 64 * NP;
    for (int i = threadIdx.x; i < 64 * 128; i += 256) {
        int c = i >> 7, r = i & 127;
        An[i] = xb[c * NP + n0 + r];
        Bm[i] = xb[c * NP + m0 + r];
    }
    __syncthreads();
    int ng = threadIdx.x & 15, mg = threadIdx.x >> 4;
    float acc[8][8];
#pragma unroll
    for (int r = 0; r < 8; r++)
#pragma unroll
        for (int j = 0; j < 8; j++) acc[r][j] = 0.0f;
    const float* ap = An + ng * 8;
    const float* bq = Bm + mg * 8;
#pragma unroll 2
    for (int c = 0; c < 64; c++) {
        float4 a0 = *(const float4*)(ap + c * 128);
        float4 a1 = *(const float4*)(ap + c * 128 + 4);
        float4 b0 = *(const float4*)(bq + c * 128);
        float4 b1 = *(const float4*)(bq + c * 128 + 4);
        float av[8] = {a0.x, a0.y, a0.z, a0.w, a1.x, a1.y, a1.z, a1.w};
        float bv[8] = {b0.x, b0.y, b0.z, b0.w, b1.x, b1.y, b1.z, b1.w};
#pragma unroll
        for (int r = 0; r < 8; r++)
#pragma unroll
            for (int j = 0; j < 8; j++) acc[r][j] += av[r] * bv[j];
    }
    float xm[8];
#pragma unroll
    for (int j = 0; j < 8; j++) xm[j] = xx2v[bp * NP + m0 + mg * 8 + j];
#pragma unroll
    for (int r = 0; r < 8; r++) {
        float xxn = xx2v[bp * NP + n0 + ng * 8 + r];
        float out[8];
#pragma unroll
        for (int j = 0; j < 8; j++) out[j] = 2.0f * acc[r][j] - xxn - xm[j];
        size_t base = ((size_t)bp * NP + n0 + ng * 8 + r) * NP + m0 + mg * 8;
        *(float4*)&Dm[base]     = make_float4(out[0], out[1], out[2], out[3]);
        *(float4*)&Dm[base + 4] = make_float4(out[4], out[5], out[6], out[7]);
    }
}

// ---------------- top-20 per row of neg_dist (wave per row) ----------------
__global__ __launch_bounds__(256) void topk2_kernel(const float* __restrict__ Dm, int* __restrict__ idx2) {
    int wid = threadIdx.x >> 6;
    int lane = threadIdx.x & 63;
    int row = blockIdx.x * 4 + wid;
    const float* dr = Dm + (size_t)row * NP;
    float v[8];
#pragma unroll
    for (int q = 0; q < 8; q++) v[q] = dr[lane + (q << 6)];
    wave_top20_set(v, lane, idx2 + (size_t)row * KK);
}

// ---------------- conv2a: A[j][o]=w2a·x1[j], Dt[n][o]=wd2·x1[n] (one GEMM) ----------
__global__ __launch_bounds__(256) void conv2a_kernel(const float* __restrict__ x1, const float* __restrict__ Wcat,
                                                     float* __restrict__ Aout, float* __restrict__ Dtout) {
    __shared__ float An[64 * 128];
    __shared__ float Bm[64 * 128];
    int bp = blockIdx.x >> 4;
    int ntb = (blockIdx.x >> 2) & 3, qtb = blockIdx.x & 3;
    int n0 = ntb * 128, q0 = qtb * 128;
    const float* xb = x1 + (size_t)bp * 64 * NP;
    for (int i = threadIdx.x; i < 64 * 128; i += 256) {
        int c = i >> 7, r = i & 127;
        An[i] = xb[c * NP + n0 + r];
        Bm[i] = Wcat[c * 512 + q0 + r];
    }
    __syncthreads();
    int ng = threadIdx.x & 15, mg = threadIdx.x >> 4;
    float acc[8][8];
#pragma unroll
    for (int r = 0; r < 8; r++)
#pragma unroll
        for (int j = 0; j < 8; j++) acc[r][j] = 0.0f;
    const float* ap = An + ng * 8;
    const float* bq = Bm + mg * 8;
#pragma unroll 2
    for (int c = 0; c < 64; c++) {
        float4 a0 = *(const float4*)(ap + c * 128);
        float4 a1 = *(const float4*)(ap + c * 128 + 4);
        float4 b0 = *(const float4*)(bq + c * 128);
        float4 b1 = *(const float4*)(bq + c * 128 + 4);
        float av[8] = {a0.x, a0.y, a0.z, a0.w, a1.x, a1.y, a1.z, a1.w};
        float bv[8] = {b0.x, b0.y, b0.z, b0.w, b1.x, b1.y, b1.z, b1.w};
#pragma unroll
        for (int r = 0; r < 8; r++)
#pragma unroll
            for (int j = 0; j < 8; j++) acc[r][j] += av[r] * bv[j];
    }
    float* ob = (q0 < 256) ? Aout : Dtout;
    int qoff = (q0 & 255) + mg * 8;
#pragma unroll
    for (int r = 0; r < 8; r++) {
        size_t base = ((size_t)bp * NP + n0 + ng * 8 + r) * 256 + qoff;
        *(float4*)&ob[base]     = make_float4(acc[r][0], acc[r][1], acc[r][2], acc[r][3]);
        *(float4*)&ob[base + 4] = make_float4(acc[r][4], acc[r][5], acc[r][6], acc[r][7]);
    }
}

// ---------------- conv2b: stats only (gather over k) ----------------
__global__ __launch_bounds__(256) void conv2b_kernel(const float* __restrict__ A, const float* __restrict__ Dt,
                                                     const int* __restrict__ idx2,
                                                     double* __restrict__ stats2) {
    __shared__ float Al[512 * 16];
    __shared__ double red[16][16][2];
    int bid = blockIdx.x;
    int bp = bid >> 5;
    int ot = (bid >> 1) & 15, nh = bid & 1;
    int o0 = ot * 16, n0 = nh * 256;
    int tid = threadIdx.x;
    for (int i = tid; i < 2048; i += 256) {
        int j = i >> 2, p = i & 3;
        *(float4*)&Al[j * 16 + p * 4] = *(const float4*)&A[((size_t)bp * NP + j) * 256 + o0 + p * 4];
    }
    __syncthreads();
    int o = tid & 15, np = tid >> 4;
    double sh = 0.0, sh2 = 0.0;
    for (int nn = 0; nn < 16; nn++) {
        int n = n0 + np * 16 + nn;
        const int* ip = idx2 + ((size_t)bp * NP + n) * KK;
        int4 ia = *(const int4*)ip, ib = *(const int4*)(ip + 4), ic = *(const int4*)(ip + 8);
        int4 id4 = *(const int4*)(ip + 12), ie = *(const int4*)(ip + 16);
        int js[20] = {ia.x, ia.y, ia.z, ia.w, ib.x, ib.y, ib.z, ib.w, ic.x, ic.y, ic.z, ic.w,
                      id4.x, id4.y, id4.z, id4.w, ie.x, ie.y, ie.z, ie.w};
        float dv = Dt[((size_t)bp * NP + n) * 256 + o0 + o];
        float s1 = 0.0f, s2 = 0.0f;
#pragma unroll
        for (int k = 0; k < KK; k++) {
            float a = Al[js[k] * 16 + o];
            s1 += a; s2 += a * a;
        }
        sh  += (double)s1 + 20.0 * (double)dv;
        sh2 += (double)s2 + 2.0 * (double)dv * (double)s1 + 20.0 * (double)dv * (double)dv;
    }
    red[np][o][0] = sh; red[np][o][1] = sh2;
    __syncthreads();
    if (tid < 16) {
        double S = 0, S2 = 0;
        for (int q = 0; q < 16; q++) { S += red[q][tid][0]; S2 += red[q][tid][1]; }
        int copy = bid & 31;
        atomicAdd(&stats2[(copy * 256 + o0 + tid) * 2], S);
        atomicAdd(&stats2[(copy * 256 + o0 + tid) * 2 + 1], S2);
    }
}

// ---------------- fin2g: re-gather, BN+lrelu, emit XC[:, 64:320] (bf16 hi/lo) --------
__global__ __launch_bounds__(256) void fin2g_kernel(const float* __restrict__ A, const float* __restrict__ Dt,
                                                    const int* __restrict__ idx2,
                                                    const float* __restrict__ scsh,
                                                    __hip_bfloat16* __restrict__ XCh,
                                                    __hip_bfloat16* __restrict__ XCl) {
    __shared__ float Al[512 * 16];
    int bid = blockIdx.x;
    int bp = bid >> 5;
    int ot = (bid >> 1) & 15, nh = bid & 1;
    int o0 = ot * 16, n0 = nh * 256;
    int tid = threadIdx.x;
    for (int i = tid; i < 2048; i += 256) {
        int j = i >> 2, p = i & 3;
        *(float4*)&Al[j * 16 + p * 4] = *(const float4*)&A[((size_t)bp * NP + j) * 256 + o0 + p * 4];
    }
    __syncthreads();
    int o = tid & 15, np = tid >> 4;
    float sc = scsh[(o0 + o) * 2], shift = scsh[(o0 + o) * 2 + 1];
    for (int nn = 0; nn < 16; nn++) {
        int n = n0 + np * 16 + nn;
        const int* ip = idx2 + ((size_t)bp * NP + n) * KK;
        int4 ia = *(const int4*)ip, ib = *(const int4*)(ip + 4), ic = *(const int4*)(ip + 8);
        int4 id4 = *(const int4*)(ip + 12), ie = *(const int4*)(ip + 16);
        int js[20] = {ia.x, ia.y, ia.z, ia.w, ib.x, ib.y, ib.z, ib.w, ic.x, ic.y, ic.z, ic.w,
                      id4.x, id4.y, id4.z, id4.w, ie.x, ie.y, ie.z, ie.w};
        float dv = Dt[((size_t)bp * NP + n) * 256 + o0 + o];
        float mx = -INFINITY, mn = INFINITY;
#pragma unroll
        for (int k = 0; k < KK; k++) {
            float a = Al[js[k] * 16 + o];
            mx = fmaxf(mx, a); mn = fminf(mn, a);
        }
        float v = ((sc >= 0.0f) ? mx : mn) + dv;
        float y = sc * v + shift;
        y = (y >= 0.0f) ? y : 0.2f * y;
        __hip_bfloat16 h = __float2bfloat16(y);
        size_t base = ((size_t)bp * NP + n) * 320 + 64 + o0 + o;
        XCh[base] = h;
        XCl[base] = __float2bfloat16(y - __bfloat162float(h));
    }
}

// ---------------- conv3m: split-bf16 MFMA GEMM (320->512), 128x64 tile, K=64 --------
// (reverted to the R11-measured 63 µs version: reg-staged, 48 KB LDS, XOR swizzle,
//  bank conflicts = 0, bitwise-identical h3)
__global__ __launch_bounds__(256) void conv3m_kernel(const __hip_bfloat16* __restrict__ XCh,
                                                     const __hip_bfloat16* __restrict__ XCl,
                                                     const __hip_bfloat16* __restrict__ w3h,
                                                     const __hip_bfloat16* __restrict__ w3l,
                                                     float* __restrict__ h3,
                                                     double* __restrict__ stats3) {
    // rows: Wh[0:128) Wl[128:256) Xh[256:320) Xl[320:384) — 384*128B = 48 KB
    __shared__ __align__(16) __hip_bfloat16 smem3[384 * 64];
    int bid = blockIdx.x;
    int bp = bid >> 5, ot = (bid >> 3) & 3, nt = bid & 7;
    int o0 = ot * 128, n0 = nt * 64;
    int tid = threadIdx.x, l = tid & 63, w = tid >> 6;
    int wo = (w >> 1) * 64, wn = (w & 1) * 32;
    int lrow = l & 15, lj = l >> 4;
    f32x4 z4 = {0.f, 0.f, 0.f, 0.f};
    f32x4 acc[4][2];
#pragma unroll
    for (int mt = 0; mt < 4; mt++) { acc[mt][0] = z4; acc[mt][1] = z4; }
    for (int ct = 0; ct < 5; ct++) {
        int c0 = ct * 64;
        __syncthreads();
        float4 vals[12];
#pragma unroll
        for (int t = 0; t < 12; t++) {
            int i = tid + t * 256;
            int row = i >> 3, ch = i & 7;
            const __hip_bfloat16* src;
            if (row < 128)      src = w3h + (size_t)(o0 + row) * 320;
            else if (row < 256) src = w3l + (size_t)(o0 + row - 128) * 320;
            else if (row < 320) src = XCh + ((size_t)bp * NP + n0 + row - 256) * 320;
            else                src = XCl + ((size_t)bp * NP + n0 + row - 320) * 320;
            vals[t] = *(const float4*)(src + c0 + ch * 8);
        }
#pragma unroll
        for (int t = 0; t < 12; t++) {
            int i = tid + t * 256;
            int row = i >> 3, ch = i & 7;
            *(float4*)(smem3 + row * 64 + ((ch ^ (row & 7)) * 8)) = vals[t];
        }
        __syncthreads();
#pragma unroll
        for (int ks = 0; ks < 2; ks++) {
            short8 ah[4], al[4], bh[2], bl[2];
#pragma unroll
            for (int t = 0; t < 4; t++) {
                int r = wo + t * 16 + lrow;
                int c = (lj + 4 * ks) ^ (r & 7);
                ah[t] = *(const short8*)(smem3 + r * 64 + c * 8);
                al[t] = *(const short8*)(smem3 + (128 + r) * 64 + c * 8);
            }
#pragma unroll
            for (int t = 0; t < 2; t++) {
                int r = wn + t * 16 + lrow;
                int c = (lj + 4 * ks) ^ (r & 7);
                bh[t] = *(const short8*)(smem3 + (256 + r) * 64 + c * 8);
                bl[t] = *(const short8*)(smem3 + (320 + r) * 64 + c * 8);
            }
#pragma unroll
            for (int mt = 0; mt < 4; mt++)
#pragma unroll
                for (int nl = 0; nl < 2; nl++) {
                    acc[mt][nl] = __builtin_amdgcn_mfma_f32_16x16x32_bf16(al[mt], bh[nl], acc[mt][nl], 0, 0, 0);
                    acc[mt][nl] = __builtin_amdgcn_mfma_f32_16x16x32_bf16(ah[mt], bl[nl], acc[mt][nl], 0, 0, 0);
                    acc[mt][nl] = __builtin_amdgcn_mfma_f32_16x16x32_bf16(ah[mt], bh[nl], acc[mt][nl], 0, 0, 0);
                }
        }
    }
    __syncthreads();                    // all LDS reads done; reuse smem for reduction
    double* redD = (double*)smem3;      // [2 n-half][128 o_local][2]
    size_t hb = (size_t)bp * 512;
#pragma unroll
    for (int mt = 0; mt < 4; mt++) {
#pragma unroll
        for (int rg = 0; rg < 4; rg++) {
            int ol = wo + mt * 16 + lj * 4 + rg;
            double s = 0.0, s2 = 0.0;
#pragma unroll
            for (int nl = 0; nl < 2; nl++) {
                float h = acc[mt][nl][rg];
                int ng = n0 + wn + nl * 16 + lrow;
                h3[(hb + o0 + ol) * 512 + ng] = h;
                s += (double)h; s2 += (double)h * (double)h;
            }
#pragma unroll
            for (int off = 1; off < 16; off <<= 1) {
                s  += __shfl_xor(s, off);
                s2 += __shfl_xor(s2, off);
            }
            if (lrow == 0) {
                redD[((w & 1) * 128 + ol) * 2]     = s;
                redD[((w & 1) * 128 + ol) * 2 + 1] = s2;
            }
        }
    }
    __syncthreads();
    if (tid < 128) {
        double S  = redD[tid * 2]     + redD[(128 + tid) * 2];
        double S2 = redD[tid * 2 + 1] + redD[(128 + tid) * 2 + 1];
        int copy = bid & 31;
        atomicAdd(&stats3[(copy * 512 + o0 + tid) * 2], S);
        atomicAdd(&stats3[(copy * 512 + o0 + tid) * 2 + 1], S2);
    }
}

// ---------------- pool: BN+lrelu then max & mean over n ----------------
__global__ __launch_bounds__(256) void pool_kernel(const float* __restrict__ h3, const float* __restrict__ scsh3,
                                                   float* __restrict__ out) {
    int row = blockIdx.x * 4 + (threadIdx.x >> 6);
    int lane = threadIdx.x & 63;
    int bp = row >> 9, o = row & 511;
    float sc = scsh3[o * 2], sh = scsh3[o * 2 + 1];
    const float* hr = h3 + (size_t)row * NP;
    float4 v0 = *(const float4*)&hr[lane * 4];
    float4 v1 = *(const float4*)&hr[256 + lane * 4];
    float vs[8] = {v0.x, v0.y, v0.z, v0.w, v1.x, v1.y, v1.z, v1.w};
    float mx = -INFINITY, sm = 0.0f;
#pragma unroll
    for (int q = 0; q < 8; q++) {
        float y = sc * vs[q] + sh;
        y = (y >= 0.0f) ? y : 0.2f * y;
        mx = fmaxf(mx, y); sm += y;
    }
    for (int off = 32; off >= 1; off >>= 1) {
        mx = fmaxf(mx, __shfl_xor(mx, off));
        sm += __shfl_xor(sm, off);
    }
    if (lane == 0) {
        out[(size_t)bp * 1024 + o]       = mx;
        out[(size_t)bp * 1024 + 512 + o] = sm * (1.0f / 512.0f);
    }
}

extern "C" void kernel_launch(void* const* d_in, const int* in_sizes, int n_in,
                              void* d_out, int out_size, void* d_ws, size_t ws_size,
                              hipStream_t stream) {
    const float* x  = (const float*)d_in[0];
    const float* w1 = (const float*)d_in[1];
    const float* g1 = (const float*)d_in[2];
    const float* b1 = (const float*)d_in[3];
    const float* w2 = (const float*)d_in[4];
    const float* g2 = (const float*)d_in[5];
    const float* b2 = (const float*)d_in[6];
    const float* w3 = (const float*)d_in[7];
    const float* g3 = (const float*)d_in[8];
    const float* b3 = (const float*)d_in[9];
    float* out = (float*)d_out;
    char* ws = (char*)d_ws;

    float*          x1    = (float*)(ws + O_X1);
    __hip_bfloat16* XCh   = (__hip_bfloat16*)(ws + O_XCH);
    __hip_bfloat16* XCl   = (__hip_bfloat16*)(ws + O_XCL);
    float*          Dbuf  = (float*)(ws + O_D);
    int*            idx   = (int*)(ws + O_IDX);
    float*          xx2v  = (float*)(ws + O_XX2);
    float*          Wcat  = (float*)(ws + O_WC);
    __hip_bfloat16* w3h   = (__hip_bfloat16*)(ws + O_W3H);
    __hip_bfloat16* w3l   = (__hip_bfloat16*)(ws + O_W3L);
    float*          scsh1 = (float*)(ws + O_SC1);
    float*          scsh2 = (float*)(ws + O_SC2);
    float*          scsh3 = (float*)(ws + O_SC3);
    double*         st1   = (double*)(ws + O_ST1);
    double*         st2   = (double*)(ws + O_ST2);
    double*         st3   = (double*)(ws + O_ST3);

    // D-region windows (sequential lifetimes)
    float* h1max = Dbuf;
    float* h1min = Dbuf + 2097152;
    float* Abuf  = Dbuf;                  // [64][512][256]
    float* Dt    = Dbuf + 8388608;        // [64][512][256] (floats; +33,554,432 B)
    float* h3    = Dbuf;                  // [64][512][512]

    hipMemsetAsync(ws + O_ST1, 0, STATS_BYTES, stream);
    prepw_kernel<<<768, 256, 0, stream>>>(w2, w3, Wcat, w3h, w3l);
    knn1_kernel<<<8192, 256, 0, stream>>>(x, idx);
    conv1_kernel<<<2048, 256, 0, stream>>>(x, w1, idx, h1max, h1min, st1);
    fprep_kernel<<<1, 256, 0, stream>>>(st1, 8, 64, 1.0 / 655360.0, g1, b1, scsh1);
    fin1_kernel<<<1024, 256, 0, stream>>>(h1max, h1min, scsh1, x1, XCh, XCl);
    xx2_kernel<<<128, 256, 0, stream>>>(x1, xx2v);
    gram_kernel<<<1024, 256, 0, stream>>>(x1, xx2v, Dbuf);
    topk2_kernel<<<8192, 256, 0, stream>>>(Dbuf, idx);
    conv2a_kernel<<<1024, 256, 0, stream>>>(x1, Wcat, Abuf, Dt);
    conv2b_kernel<<<2048, 256, 0, stream>>>(Abuf, Dt, idx, st2);
    fprep_kernel<<<1, 256, 0, stream>>>(st2, 32, 256, 1.0 / 655360.0, g2, b2, scsh2);
    fin2g_kernel<<<2048, 256, 0, stream>>>(Abuf, Dt, idx, scsh2, XCh, XCl);
    conv3m_kernel<<<2048, 256, 0, stream>>>(XCh, XCl, w3h, w3l, h3, st3);
    fprep_kernel<<<2, 256, 0, stream>>>(st3, 32, 512, 1.0 / 32768.0, g3, b3, scsh3);
    pool_kernel<<<8192, 256, 0, stream>>>(h3, scsh3, out);
}